// Round 7
// baseline (73.069 us; speedup 1.0000x reference)
//
#include <hip/hip_runtime.h>
#include <hip/hip_bf16.h>
#include <math.h>

#define DD 256      // feature dim
#define SS 1024     // seq len
#define BB 8        // batch
#define NN 128      // nodes
#define TOK 16      // tokens per scorer block
#define KC 64       // k-chunk for fallback scorer
#define PNT 16      // nodes per pool block
#define PSC 16      // S-chunks in pool
#define PSCH (SS/PSC)  // 64

// ================= Kernel 1: fused scorer MLP -> scores (B*S) =================
// h = x @ W1 + b1 ; LN(h) ; GELU(erf) ; score = h @ W2 + b2
// 4 waves/block, wave owns 4 tokens; thread owns 4 W1 columns (c0 = 4*lane).
// W1: coalesced per-lane float4 from L2, 16 rows held in registers per chunk.
// x: WAVE-UNIFORM addresses -> scalar (s_load) path, no LDS, no VMEM pressure.
__global__ __launch_bounds__(256) void scorer_fused_kernel(
    const float* __restrict__ doc, const float* __restrict__ W1,
    const float* __restrict__ b1, const float* __restrict__ gamma,
    const float* __restrict__ beta, const float* __restrict__ W2,
    const float* __restrict__ b2, float* __restrict__ scores)
{
    const int tid  = threadIdx.x;
    const int lane = tid & 63;
    const int wave = __builtin_amdgcn_readfirstlane(tid >> 6);  // force uniform
    const int c0   = lane * 4;
    const int t0   = blockIdx.x * TOK + wave * 4;   // this wave's 4 token rows

    float4 acc[4];
    const float4 bv = *reinterpret_cast<const float4*>(b1 + c0);
#pragma unroll
    for (int t = 0; t < 4; ++t) acc[t] = bv;

    const float* w1c = W1 + c0;

#pragma unroll 1
    for (int kb = 0; kb < DD; kb += 16) {
        // 16 W1 rows x 4 cols per lane (coalesced b128), held in 64 VGPRs
        float4 wr[16];
#pragma unroll
        for (int i = 0; i < 16; ++i)
            wr[i] = *reinterpret_cast<const float4*>(w1c + (size_t)(kb + i) * DD);

        // x slices: wave-uniform -> scalar loads
        float4 xv[4][4];
#pragma unroll
        for (int t = 0; t < 4; ++t)
#pragma unroll
            for (int j = 0; j < 4; ++j)
                xv[t][j] = *reinterpret_cast<const float4*>(
                    doc + (size_t)(t0 + t) * DD + kb + 4 * j);

#pragma unroll
        for (int t = 0; t < 4; ++t) {
#pragma unroll
            for (int j = 0; j < 4; ++j) {
                const float4 x4 = xv[t][j];
                const float4 wa = wr[4 * j + 0];
                const float4 wb = wr[4 * j + 1];
                const float4 wc = wr[4 * j + 2];
                const float4 wd = wr[4 * j + 3];
                acc[t].x = fmaf(x4.x, wa.x, acc[t].x);
                acc[t].y = fmaf(x4.x, wa.y, acc[t].y);
                acc[t].z = fmaf(x4.x, wa.z, acc[t].z);
                acc[t].w = fmaf(x4.x, wa.w, acc[t].w);
                acc[t].x = fmaf(x4.y, wb.x, acc[t].x);
                acc[t].y = fmaf(x4.y, wb.y, acc[t].y);
                acc[t].z = fmaf(x4.y, wb.z, acc[t].z);
                acc[t].w = fmaf(x4.y, wb.w, acc[t].w);
                acc[t].x = fmaf(x4.z, wc.x, acc[t].x);
                acc[t].y = fmaf(x4.z, wc.y, acc[t].y);
                acc[t].z = fmaf(x4.z, wc.z, acc[t].z);
                acc[t].w = fmaf(x4.z, wc.w, acc[t].w);
                acc[t].x = fmaf(x4.w, wd.x, acc[t].x);
                acc[t].y = fmaf(x4.w, wd.y, acc[t].y);
                acc[t].z = fmaf(x4.w, wd.z, acc[t].z);
                acc[t].w = fmaf(x4.w, wd.w, acc[t].w);
            }
        }
    }

    // LayerNorm + GELU + dot(W2) — registers + wave shuffles
    const float4 gm  = *reinterpret_cast<const float4*>(gamma + c0);
    const float4 be  = *reinterpret_cast<const float4*>(beta + c0);
    const float4 w2v = *reinterpret_cast<const float4*>(W2 + c0);
    const float  b2v = b2[0];

#pragma unroll
    for (int t = 0; t < 4; ++t) {
        float s1 = acc[t].x + acc[t].y + acc[t].z + acc[t].w;
        float s2 = acc[t].x * acc[t].x + acc[t].y * acc[t].y
                 + acc[t].z * acc[t].z + acc[t].w * acc[t].w;
#pragma unroll
        for (int off = 32; off > 0; off >>= 1) {
            s1 += __shfl_xor(s1, off, 64);
            s2 += __shfl_xor(s2, off, 64);
        }
        const float mean = s1 * (1.f / DD);
        const float var  = s2 * (1.f / DD) - mean * mean;
        const float inv  = rsqrtf(var + 1e-5f);

        const float n0 = (acc[t].x - mean) * inv * gm.x + be.x;
        const float n1 = (acc[t].y - mean) * inv * gm.y + be.y;
        const float n2 = (acc[t].z - mean) * inv * gm.z + be.z;
        const float n3 = (acc[t].w - mean) * inv * gm.w + be.w;
        const float kq = 0.70710678118654752f;
        const float g0 = 0.5f * n0 * (1.f + erff(n0 * kq));
        const float g1 = 0.5f * n1 * (1.f + erff(n1 * kq));
        const float g2 = 0.5f * n2 * (1.f + erff(n2 * kq));
        const float g3 = 0.5f * n3 * (1.f + erff(n3 * kq));
        float sc = g0 * w2v.x + g1 * w2v.y + g2 * w2v.z + g3 * w2v.w;
#pragma unroll
        for (int off = 32; off > 0; off >>= 1) sc += __shfl_xor(sc, off, 64);
        if (lane == 0) scores[t0 + t] = sc + b2v;
    }
}

// ====== Kernel 2: per-node masked softmax -> materialized weights w[b][n][s] ======
__global__ __launch_bounds__(256) void statsw_kernel(
    const float* __restrict__ mapping, const float* __restrict__ scores,
    float* __restrict__ w)
{
    __shared__ float sc_s[SS];
    const int tid  = threadIdx.x, lane = tid & 63;
    const int wave = __builtin_amdgcn_readfirstlane(tid >> 6);
    const int g0   = blockIdx.x * 4;     // 4 nodes per block, same batch
    const int b    = g0 >> 7;

    reinterpret_cast<float4*>(sc_s)[tid] =
        reinterpret_cast<const float4*>(scores + (size_t)b * SS)[tid];
    __syncthreads();

    const int g = g0 + wave;
    const float4* mrow4 = reinterpret_cast<const float4*>(mapping + (size_t)g * SS);
    const float4* sc4   = reinterpret_cast<const float4*>(sc_s);

    float4 mv[4], sv[4];
    float mx = -INFINITY;
#pragma unroll
    for (int q = 0; q < 4; ++q) {
        mv[q] = mrow4[lane + (q << 6)];
        sv[q] = sc4[lane + (q << 6)];
        if (mv[q].x > 0.5f) mx = fmaxf(mx, sv[q].x);
        if (mv[q].y > 0.5f) mx = fmaxf(mx, sv[q].y);
        if (mv[q].z > 0.5f) mx = fmaxf(mx, sv[q].z);
        if (mv[q].w > 0.5f) mx = fmaxf(mx, sv[q].w);
    }
#pragma unroll
    for (int off = 32; off > 0; off >>= 1) mx = fmaxf(mx, __shfl_xor(mx, off, 64));
    float z = 0.f;
    float4 ev[4];
#pragma unroll
    for (int q = 0; q < 4; ++q) {
        ev[q].x = (mv[q].x > 0.5f) ? __expf(sv[q].x - mx) : 0.f;
        ev[q].y = (mv[q].y > 0.5f) ? __expf(sv[q].y - mx) : 0.f;
        ev[q].z = (mv[q].z > 0.5f) ? __expf(sv[q].z - mx) : 0.f;
        ev[q].w = (mv[q].w > 0.5f) ? __expf(sv[q].w - mx) : 0.f;
        z += ev[q].x + ev[q].y + ev[q].z + ev[q].w;
    }
#pragma unroll
    for (int off = 32; off > 0; off >>= 1) z += __shfl_xor(z, off, 64);
    const float invz = (z > 0.f) ? (1.f / z) : 0.f;

    float4* wrow4 = reinterpret_cast<float4*>(w + (size_t)g * SS);
#pragma unroll
    for (int q = 0; q < 4; ++q) {
        float4 e;
        e.x = ev[q].x * invz; e.y = ev[q].y * invz;
        e.z = ev[q].z * invz; e.w = ev[q].w * invz;
        wrow4[lane + (q << 6)] = e;
    }
}

// ====== Kernel 3: pooled partials. thread owns dim d; weights via scalar loads ======
// blockIdx: c = blk&15 (S-chunk), nt = (blk>>4)&7 (16-node tile), b = blk>>7.
__global__ __launch_bounds__(256) void pool16_kernel(
    const float* __restrict__ doc, const float* __restrict__ w,
    float* __restrict__ part)
{
    const int blk = blockIdx.x;
    const int c   = blk & (PSC - 1);
    const int nt  = (blk >> 4) & 7;
    const int b   = blk >> 7;
    const int s0  = c * PSCH;
    const int d   = threadIdx.x;

    float acc[PNT];
#pragma unroll
    for (int n = 0; n < PNT; ++n) acc[n] = 0.f;

    const float* docb = doc + ((size_t)b * SS + s0) * DD;
    const float* wb   = w + ((size_t)(b * NN + nt * PNT)) * SS + s0;

#pragma unroll 1
    for (int sb = 0; sb < PSCH; sb += 16) {
        float dr[16];
#pragma unroll
        for (int j = 0; j < 16; ++j)
            dr[j] = docb[(size_t)(sb + j) * DD + d];

#pragma unroll
        for (int n = 0; n < PNT; ++n) {
            const float* wn = wb + (size_t)n * SS + sb;   // block-uniform -> s_load
            const float4 w0 = *reinterpret_cast<const float4*>(wn);
            const float4 w1 = *reinterpret_cast<const float4*>(wn + 4);
            const float4 w2 = *reinterpret_cast<const float4*>(wn + 8);
            const float4 w3 = *reinterpret_cast<const float4*>(wn + 12);
            float a = acc[n];
            a = fmaf(w0.x, dr[0],  a);
            a = fmaf(w0.y, dr[1],  a);
            a = fmaf(w0.z, dr[2],  a);
            a = fmaf(w0.w, dr[3],  a);
            a = fmaf(w1.x, dr[4],  a);
            a = fmaf(w1.y, dr[5],  a);
            a = fmaf(w1.z, dr[6],  a);
            a = fmaf(w1.w, dr[7],  a);
            a = fmaf(w2.x, dr[8],  a);
            a = fmaf(w2.y, dr[9],  a);
            a = fmaf(w2.z, dr[10], a);
            a = fmaf(w2.w, dr[11], a);
            a = fmaf(w3.x, dr[12], a);
            a = fmaf(w3.y, dr[13], a);
            a = fmaf(w3.z, dr[14], a);
            a = fmaf(w3.w, dr[15], a);
            acc[n] = a;
        }
    }

    float* p = part + (size_t)blk * (PNT * DD);
#pragma unroll
    for (int n = 0; n < PNT; ++n) p[(size_t)n * DD + d] = acc[n];
}

// ---------------- Kernel 4: reduce PSC partials ----------------
__global__ __launch_bounds__(256) void reduce16_kernel(
    const float* __restrict__ part, float* __restrict__ out)
{
    const int o = blockIdx.x * 256 + threadIdx.x;   // B*N*D = 262144
    const int d = o & 255;
    const int g = o >> 8;          // b*128 + n
    const int b = g >> 7;
    const int n = g & 127;
    const int nt = n >> 4, nl = n & 15;
    const size_t base = ((size_t)(b * 128 + nt * 16)) * (PNT * DD)
                      + (size_t)nl * DD + d;
    float s = 0.f;
#pragma unroll
    for (int c = 0; c < PSC; ++c) s += part[base + (size_t)c * (PNT * DD)];
    out[o] = s;
}

// ================= Fallback path (tiny ws): r5 monolithic kernels =================
__global__ __launch_bounds__(256) void scorer_kernel(
    const float* __restrict__ doc, const float* __restrict__ W1,
    const float* __restrict__ b1, const float* __restrict__ gamma,
    const float* __restrict__ beta, const float* __restrict__ W2,
    const float* __restrict__ b2, float* __restrict__ scores)
{
    __shared__ float xs[TOK][DD];
    __shared__ float w1s[KC][DD];

    const int tid  = threadIdx.x;
    const int wave = tid >> 6, lane = tid & 63;
    const int t0   = blockIdx.x * TOK;
    const int c0   = lane * 4;

    {
        const float4* src = reinterpret_cast<const float4*>(doc + (size_t)t0 * DD);
        float4* dst = reinterpret_cast<float4*>(&xs[0][0]);
#pragma unroll
        for (int r = 0; r < 4; ++r) dst[tid + 256 * r] = src[tid + 256 * r];
    }

    float4 acc[4];
    {
        const float4 bv = *reinterpret_cast<const float4*>(b1 + c0);
#pragma unroll
        for (int t = 0; t < 4; ++t) acc[t] = bv;
    }
    const float* xw = &xs[wave * 4][0];

    for (int kc = 0; kc < DD / KC; ++kc) {
        __syncthreads();
        {
            const float4* wsrc = reinterpret_cast<const float4*>(W1 + (size_t)kc * KC * DD);
            float4* wdst = reinterpret_cast<float4*>(&w1s[0][0]);
#pragma unroll
            for (int r = 0; r < 16; ++r) wdst[tid + 256 * r] = wsrc[tid + 256 * r];
        }
        __syncthreads();
#pragma unroll 4
        for (int k4 = 0; k4 < KC / 4; ++k4) {
            const int kb = k4 * 4;
            const float4 w0 = *reinterpret_cast<const float4*>(&w1s[kb + 0][c0]);
            const float4 w1 = *reinterpret_cast<const float4*>(&w1s[kb + 1][c0]);
            const float4 w2 = *reinterpret_cast<const float4*>(&w1s[kb + 2][c0]);
            const float4 w3 = *reinterpret_cast<const float4*>(&w1s[kb + 3][c0]);
#pragma unroll
            for (int t = 0; t < 4; ++t) {
                const float4 xv = *reinterpret_cast<const float4*>(xw + (size_t)t * DD + kc * KC + kb);
                acc[t].x = fmaf(xv.x, w0.x, acc[t].x);
                acc[t].y = fmaf(xv.x, w0.y, acc[t].y);
                acc[t].z = fmaf(xv.x, w0.z, acc[t].z);
                acc[t].w = fmaf(xv.x, w0.w, acc[t].w);
                acc[t].x = fmaf(xv.y, w1.x, acc[t].x);
                acc[t].y = fmaf(xv.y, w1.y, acc[t].y);
                acc[t].z = fmaf(xv.y, w1.z, acc[t].z);
                acc[t].w = fmaf(xv.y, w1.w, acc[t].w);
                acc[t].x = fmaf(xv.z, w2.x, acc[t].x);
                acc[t].y = fmaf(xv.z, w2.y, acc[t].y);
                acc[t].z = fmaf(xv.z, w2.z, acc[t].z);
                acc[t].w = fmaf(xv.z, w2.w, acc[t].w);
                acc[t].x = fmaf(xv.w, w3.x, acc[t].x);
                acc[t].y = fmaf(xv.w, w3.y, acc[t].y);
                acc[t].z = fmaf(xv.w, w3.z, acc[t].z);
                acc[t].w = fmaf(xv.w, w3.w, acc[t].w);
            }
        }
    }

    const float4 gm = *reinterpret_cast<const float4*>(gamma + c0);
    const float4 be = *reinterpret_cast<const float4*>(beta + c0);
    const float4 w2v = *reinterpret_cast<const float4*>(W2 + c0);
    const float b2v = b2[0];

#pragma unroll
    for (int t = 0; t < 4; ++t) {
        float s1 = acc[t].x + acc[t].y + acc[t].z + acc[t].w;
        float s2 = acc[t].x * acc[t].x + acc[t].y * acc[t].y
                 + acc[t].z * acc[t].z + acc[t].w * acc[t].w;
#pragma unroll
        for (int off = 32; off > 0; off >>= 1) {
            s1 += __shfl_xor(s1, off, 64);
            s2 += __shfl_xor(s2, off, 64);
        }
        const float mean = s1 * (1.f / DD);
        const float var  = s2 * (1.f / DD) - mean * mean;
        const float inv  = rsqrtf(var + 1e-5f);
        float n0 = (acc[t].x - mean) * inv * gm.x + be.x;
        float n1 = (acc[t].y - mean) * inv * gm.y + be.y;
        float n2 = (acc[t].z - mean) * inv * gm.z + be.z;
        float n3 = (acc[t].w - mean) * inv * gm.w + be.w;
        const float kq = 0.70710678118654752f;
        float g0 = 0.5f * n0 * (1.f + erff(n0 * kq));
        float g1 = 0.5f * n1 * (1.f + erff(n1 * kq));
        float g2 = 0.5f * n2 * (1.f + erff(n2 * kq));
        float g3 = 0.5f * n3 * (1.f + erff(n3 * kq));
        float sc = g0 * w2v.x + g1 * w2v.y + g2 * w2v.z + g3 * w2v.w;
#pragma unroll
        for (int off = 32; off > 0; off >>= 1) sc += __shfl_xor(sc, off, 64);
        if (lane == 0) scores[t0 + wave * 4 + t] = sc + b2v;
    }
}

__global__ __launch_bounds__(256) void stats_kernel(
    const float* __restrict__ mapping, const float* __restrict__ scores,
    float* __restrict__ mx_out, float* __restrict__ invz_out)
{
    __shared__ float sc_s[SS];
    const int tid = threadIdx.x, wave = tid >> 6, lane = tid & 63;
    const int g0 = blockIdx.x * 4;
    const int b  = g0 >> 7;

    reinterpret_cast<float4*>(sc_s)[tid] =
        reinterpret_cast<const float4*>(scores + (size_t)b * SS)[tid];
    __syncthreads();

    const int g = g0 + wave;
    const float4* mrow4 = reinterpret_cast<const float4*>(mapping + (size_t)g * SS);
    const float4* sc4   = reinterpret_cast<const float4*>(sc_s);

    float4 mv[4], sv[4];
    float mx = -INFINITY;
#pragma unroll
    for (int q = 0; q < 4; ++q) {
        mv[q] = mrow4[lane + (q << 6)];
        sv[q] = sc4[lane + (q << 6)];
        if (mv[q].x > 0.5f) mx = fmaxf(mx, sv[q].x);
        if (mv[q].y > 0.5f) mx = fmaxf(mx, sv[q].y);
        if (mv[q].z > 0.5f) mx = fmaxf(mx, sv[q].z);
        if (mv[q].w > 0.5f) mx = fmaxf(mx, sv[q].w);
    }
#pragma unroll
    for (int off = 32; off > 0; off >>= 1) mx = fmaxf(mx, __shfl_xor(mx, off, 64));
    float z = 0.f;
#pragma unroll
    for (int q = 0; q < 4; ++q) {
        if (mv[q].x > 0.5f) z += __expf(sv[q].x - mx);
        if (mv[q].y > 0.5f) z += __expf(sv[q].y - mx);
        if (mv[q].z > 0.5f) z += __expf(sv[q].z - mx);
        if (mv[q].w > 0.5f) z += __expf(sv[q].w - mx);
    }
#pragma unroll
    for (int off = 32; off > 0; off >>= 1) z += __shfl_xor(z, off, 64);
    if (lane == 0) {
        mx_out[g]   = mx;
        invz_out[g] = (z > 0.f) ? (1.f / z) : 0.f;
    }
}

// fallback pool: whole S per block, 8 nodes, writes out directly
__global__ __launch_bounds__(256) void pool_direct_kernel(
    const float* __restrict__ doc, const float* __restrict__ mapping,
    const float* __restrict__ scores, const float* __restrict__ mx_in,
    const float* __restrict__ invz_in, float* __restrict__ out)
{
    __shared__ float w_lds[8][SS];   // 32 KiB

    const int bt    = blockIdx.x;
    const int ntile = bt & 15;
    const int b     = bt >> 4;
    const int tid = threadIdx.x, wave = tid >> 6, lane = tid & 63;

    {
        const int nl = wave * 2 + (lane >> 5);
        const int g  = b * NN + ntile * 8 + nl;
        const float mx   = mx_in[g];
        const float invz = invz_in[g];
        const float4* mrow4 = reinterpret_cast<const float4*>(mapping + (size_t)g * SS);
        const float4* srow4 = reinterpret_cast<const float4*>(scores + (size_t)b * SS);
        float4* wrow4 = reinterpret_cast<float4*>(&w_lds[nl][0]);
        const int idx0 = lane & 31;
#pragma unroll
        for (int q = 0; q < SS / 128; ++q) {
            const int idx = idx0 + 32 * q;
            const float4 mp = mrow4[idx];
            const float4 sv = srow4[idx];
            float4 e;
            e.x = (mp.x > 0.5f) ? __expf(sv.x - mx) * invz : 0.f;
            e.y = (mp.y > 0.5f) ? __expf(sv.y - mx) * invz : 0.f;
            e.z = (mp.z > 0.5f) ? __expf(sv.z - mx) * invz : 0.f;
            e.w = (mp.w > 0.5f) ? __expf(sv.w - mx) * invz : 0.f;
            wrow4[idx] = e;
        }
    }
    __syncthreads();

    float acc[8];
#pragma unroll
    for (int n = 0; n < 8; ++n) acc[n] = 0.f;
    const float* docb = doc + (size_t)b * SS * DD;

    for (int s4 = 0; s4 < SS; s4 += 4) {
        const float d0 = docb[(size_t)(s4 + 0) * DD + tid];
        const float d1 = docb[(size_t)(s4 + 1) * DD + tid];
        const float d2 = docb[(size_t)(s4 + 2) * DD + tid];
        const float d3 = docb[(size_t)(s4 + 3) * DD + tid];
#pragma unroll
        for (int n = 0; n < 8; ++n) {
            const float4 wv = *reinterpret_cast<const float4*>(&w_lds[n][s4]);
            acc[n] = fmaf(wv.x, d0, acc[n]);
            acc[n] = fmaf(wv.y, d1, acc[n]);
            acc[n] = fmaf(wv.z, d2, acc[n]);
            acc[n] = fmaf(wv.w, d3, acc[n]);
        }
    }

    float* outb = out + (((size_t)b * NN) + (size_t)ntile * 8) * DD;
#pragma unroll
    for (int n = 0; n < 8; ++n) outb[(size_t)n * DD + tid] = acc[n];
}

extern "C" void kernel_launch(void* const* d_in, const int* in_sizes, int n_in,
                              void* d_out, int out_size, void* d_ws, size_t ws_size,
                              hipStream_t stream) {
    const float* doc     = (const float*)d_in[0];  // (B,S,D)
    const float* mapping = (const float*)d_in[1];  // (B,N,S)
    // d_in[2] = nodes_len (unused)
    const float* W1    = (const float*)d_in[3];    // (D,D)
    const float* b1    = (const float*)d_in[4];    // (D)
    const float* gamma = (const float*)d_in[5];    // (D)
    const float* beta  = (const float*)d_in[6];    // (D)
    const float* W2    = (const float*)d_in[7];    // (D,1)
    const float* b2    = (const float*)d_in[8];    // (1)
    float* out = (float*)d_out;                    // (B,N,D)

    float* scores = (float*)d_ws;                              // 8192 f32
    float* w      = scores + BB * SS;                          // B*N*S = 4 MiB
    float* part   = w + (size_t)BB * NN * SS;                  // 1024*16*256 = 16 MiB

    const size_t need = ((size_t)BB * SS + (size_t)BB * NN * SS
                       + (size_t)BB * NN * PSC * DD * 2) * 4;  // ~21 MB (part = PSC*PNT*DD per 128 blocks... generous)

    if (ws_size >= need) {
        scorer_fused_kernel<<<BB * SS / TOK, 256, 0, stream>>>(doc, W1, b1, gamma, beta, W2, b2, scores);
        statsw_kernel<<<(BB * NN) / 4, 256, 0, stream>>>(mapping, scores, w);
        pool16_kernel<<<BB * (NN / PNT) * PSC, 256, 0, stream>>>(doc, w, part);
        reduce16_kernel<<<(BB * NN * DD) / 256, 256, 0, stream>>>(part, out);
    } else {
        float* mx   = scores + BB * SS;
        float* invz = mx + BB * NN;
        scorer_kernel<<<BB * SS / TOK, 256, 0, stream>>>(doc, W1, b1, gamma, beta, W2, b2, scores);
        stats_kernel<<<(BB * NN) / 4, 256, 0, stream>>>(mapping, scores, mx, invz);
        pool_direct_kernel<<<BB * 16, 256, 0, stream>>>(doc, mapping, scores, mx, invz, out);
    }
}